// Round 1
// baseline (31.818 us; speedup 1.0000x reference)
//
#include <hip/hip_runtime.h>

#define NRAD  8
#define RM    32      // NUM_RADIAL * NUM_ANGULAR
#define S     512
#define CIN   16
#define COUT  16
#define ATILE 8
#define BTILE 32

// grid: 4 z * 64 a-tiles = 256 blocks, 256 threads each.
// Per block: out[z, a0..a0+7, :] fully computed (all 512 b).
__global__ __launch_bounds__(256)
void econv_kernel(const float* __restrict__ feat,   // [4][512][16]
                  const float* __restrict__ geom,   // [4][512][3]
                  const float* __restrict__ Wm,     // [8][4][16][16]
                  const int*   __restrict__ n_norm, // [1]
                  float*       __restrict__ out)    // [4][512][16]
{
    __shared__ float Glds[S * 3];                // 6 KB  geometry[z]
    __shared__ float Ftile[BTILE * CIN];         // 2 KB  feature tile
    __shared__ float Blds[ATILE * BTILE * RM];   // 32 KB basis tile (reused as T)

    const int t  = threadIdx.x;
    const int z  = blockIdx.x >> 6;
    const int a0 = (blockIdx.x & 63) * ATILE;

    const float* gz = geom + z * S * 3;
    const float* fz = feat + z * S * CIN;

    // stage geometry[z] (1536 floats, coalesced)
#pragma unroll
    for (int k = 0; k < (S * 3) / 256; ++k)
        Glds[k * 256 + t] = gz[k * 256 + t];
    __syncthreads();

    // thread roles for the FMA phase: (a_loc, rm-quad, j-quad)
    const int a_loc = t >> 5;        // 0..7
    const int s     = t & 31;
    const int rmg   = s >> 2;        // quad index == r (rm = 4*r + m)
    const int jg    = s & 3;         // j quad

    const int aa = a0 + a_loc;
    const float gax = Glds[3 * aa + 0];
    const float gay = Glds[3 * aa + 1];
    const float gaz = Glds[3 * aa + 2];

    float acc[4][4];
#pragma unroll
    for (int u = 0; u < 4; ++u)
#pragma unroll
        for (int v = 0; v < 4; ++v) acc[u][v] = 0.f;

    for (int b0 = 0; b0 < S; b0 += BTILE) {
        __syncthreads();   // previous tile's Blds/Ftile fully consumed

        // stage feature tile: 512 floats via float2 per thread (coalesced)
        ((float2*)Ftile)[t] = ((const float2*)(fz + b0 * CIN))[t];

        // compute basis for one (a_loc, b) pair per thread
        {
            const int bb = s;            // b_loc 0..31
            const int b  = b0 + bb;
            float dx = Glds[3 * b + 0] - gax;
            float dy = Glds[3 * b + 1] - gay;
            float dz = Glds[3 * b + 2] - gaz;
            float ss  = fmaf(dx, dx, fmaf(dy, dy, fmaf(dz, dz, 1e-12f)));
            float inv = rsqrtf(ss);
            float d   = ss * inv;                    // sqrt(ss)
            float ux = dx * inv, uy = dy * inv, uz = dz * inv;
            float* brow = &Blds[(a_loc * BTILE + bb) * RM];
            const int sw = bb & 7;                   // XOR swizzle key
#pragma unroll
            for (int r = 0; r < NRAD; ++r) {
                float e   = d - (float)r * (3.0f / 7.0f);
                float rad = __expf(-8.0f * e * e);
                float4 q;
                q.x = rad;        // m=0: constant
                q.y = rad * ux;   // m=1
                q.z = rad * uy;   // m=2
                q.w = rad * uz;   // m=3
                *(float4*)(brow + ((r ^ sw) << 2)) = q;
            }
        }
        __syncthreads();   // Blds/Ftile ready

        // accumulate T[a_loc, 4rmg+u, 4jg+v] over this b tile
#pragma unroll
        for (int bb = 0; bb < BTILE; ++bb) {
            float4 Bv = *(const float4*)(&Blds[(a_loc * BTILE + bb) * RM +
                                              ((rmg ^ (bb & 7)) << 2)]);
            float4 Fv = *(const float4*)(&Ftile[bb * CIN + (jg << 2)]);
            float Bk[4] = {Bv.x, Bv.y, Bv.z, Bv.w};
            float Fk[4] = {Fv.x, Fv.y, Fv.z, Fv.w};
#pragma unroll
            for (int u = 0; u < 4; ++u)
#pragma unroll
                for (int v = 0; v < 4; ++v)
                    acc[u][v] = fmaf(Bk[u], Fk[v], acc[u][v]);
        }
    }

    // ---- epilogue: T (LDS, reuse Blds) then contract with W ----
    __syncthreads();
#pragma unroll
    for (int u = 0; u < 4; ++u) {
        float4 q;
        q.x = acc[u][0]; q.y = acc[u][1]; q.z = acc[u][2]; q.w = acc[u][3];
        *(float4*)(&Blds[(a_loc * RM + (rmg * 4 + u)) * CIN + (jg << 2)]) = q;
    }
    __syncthreads();

    if (t < ATILE * COUT) {
        const int al = t >> 4;
        const int i  = t & 15;
        float o = 0.f;
        const float* T = &Blds[al * RM * CIN];
#pragma unroll
        for (int rm = 0; rm < RM; ++rm) {
#pragma unroll
            for (int j = 0; j < CIN; j += 4) {
                float4 tv = *(const float4*)(T + rm * CIN + j);
                float4 wv = *(const float4*)(Wm + (rm * COUT + i) * CIN + j);
                o = fmaf(tv.x, wv.x, o);
                o = fmaf(tv.y, wv.y, o);
                o = fmaf(tv.z, wv.z, o);
                o = fmaf(tv.w, wv.w, o);
            }
        }
        const float scale = rsqrtf((float)n_norm[0]);  // 1/sqrt(512)
        out[(z * S + a0 + al) * COUT + i] = o * scale;
    }
}

extern "C" void kernel_launch(void* const* d_in, const int* in_sizes, int n_in,
                              void* d_out, int out_size, void* d_ws, size_t ws_size,
                              hipStream_t stream) {
    const float* feat   = (const float*)d_in[0];
    const float* geomp  = (const float*)d_in[1];
    const float* Wm     = (const float*)d_in[2];
    const int*   n_norm = (const int*)d_in[3];
    float* outp = (float*)d_out;

    dim3 grid(256), block(256);
    econv_kernel<<<grid, block, 0, stream>>>(feat, geomp, Wm, n_norm, outp);
}

// Round 2
// 30.245 us; speedup vs baseline: 1.0520x; 1.0520x over previous
//
#include <hip/hip_runtime.h>

#define NRAD  8
#define RM    32      // NUM_RADIAL * NUM_ANGULAR
#define S     512
#define CIN   16
#define COUT  16
#define ATILE 4
#define BTILE 64
#define NTILES (S / BTILE)   // 8

// grid: 4 z * 128 a-tiles = 512 blocks (2 per CU), 256 threads.
// Each wave owns one a; lane halves split the b range; shfl_xor(32) reduces.
__global__ __launch_bounds__(256, 2)
void econv_kernel(const float* __restrict__ feat,   // [4][512][16]
                  const float* __restrict__ geom,   // [4][512][3]
                  const float* __restrict__ Wm,     // [8][4][16][16]
                  const int*   __restrict__ n_norm, // [1]
                  float*       __restrict__ out)    // [4][512][16]
{
    __shared__ float Glds[S * 3];                // 6 KB  geometry[z]
    __shared__ float Ftile[BTILE * CIN];         // 4 KB  feature tile
    __shared__ float Blds[ATILE * BTILE * RM];   // 32 KB basis tile (reused as T)

    const int t  = threadIdx.x;
    const int z  = blockIdx.x >> 7;
    const int a0 = (blockIdx.x & 127) * ATILE;

    const float* gz = geom + z * S * 3;
    const float* fz = feat + z * S * CIN;

    // stage geometry[z] (1536 floats, coalesced)
#pragma unroll
    for (int k = 0; k < (S * 3) / 256; ++k)
        Glds[k * 256 + t] = gz[k * 256 + t];
    __syncthreads();

    // thread roles
    const int a_loc = t >> 6;        // wave index == local a (0..3)
    const int l     = t & 63;        // lane
    const int bhalf = l >> 5;        // b-half within tile
    const int s2    = l & 31;
    const int rmg   = s2 >> 2;       // rm quad (0..7)
    const int jg    = s2 & 3;        // j quad (0..3)

    const int aa = a0 + a_loc;
    const float gax = Glds[3 * aa + 0];
    const float gay = Glds[3 * aa + 1];
    const float gaz = Glds[3 * aa + 2];

    float acc[4][4];
#pragma unroll
    for (int u = 0; u < 4; ++u)
#pragma unroll
        for (int v = 0; v < 4; ++v) acc[u][v] = 0.f;

    for (int b0 = 0; b0 < S; b0 += BTILE) {
        __syncthreads();   // previous tile fully consumed

        // stage feature tile: BTILE*CIN = 1024 floats via float4 (coalesced)
        ((float4*)Ftile)[t] = ((const float4*)(fz + b0 * CIN))[t];

        // basis for one (a_loc, bb=l) pair per thread
        {
            const int bb = l;
            const int b  = b0 + bb;
            float dx = Glds[3 * b + 0] - gax;
            float dy = Glds[3 * b + 1] - gay;
            float dz = Glds[3 * b + 2] - gaz;
            float ss  = fmaf(dx, dx, fmaf(dy, dy, fmaf(dz, dz, 1e-12f)));
            float inv = rsqrtf(ss);
            float d   = ss * inv;                    // sqrt(ss)
            float ux = dx * inv, uy = dy * inv, uz = dz * inv;
            float* brow = &Blds[(a_loc * BTILE + bb) * RM];
            const int sw = bb & 7;                   // XOR swizzle key
#pragma unroll
            for (int r = 0; r < NRAD; ++r) {
                float e   = d - (float)r * (3.0f / 7.0f);
                float rad = __expf(-8.0f * e * e);
                float4 q;
                q.x = rad;        // m=0: constant
                q.y = rad * ux;   // m=1
                q.z = rad * uy;   // m=2
                q.w = rad * uz;   // m=3
                *(float4*)(brow + ((r ^ sw) << 2)) = q;
            }
        }
        __syncthreads();   // Blds/Ftile ready

        // accumulate over this tile; this thread covers bb = bhalf*32 + i
#pragma unroll
        for (int i = 0; i < 32; ++i) {
            const int bb = bhalf * 32 + i;
            float4 Bv = *(const float4*)(&Blds[(a_loc * BTILE + bb) * RM +
                                              ((rmg ^ (i & 7)) << 2)]);
            float4 Fv = *(const float4*)(&Ftile[bb * CIN + (jg << 2)]);
            float Bk[4] = {Bv.x, Bv.y, Bv.z, Bv.w};
            float Fk[4] = {Fv.x, Fv.y, Fv.z, Fv.w};
#pragma unroll
            for (int u = 0; u < 4; ++u)
#pragma unroll
                for (int v = 0; v < 4; ++v)
                    acc[u][v] = fmaf(Bk[u], Fk[v], acc[u][v]);
        }
    }

    // ---- reduce the 2-way b-split in-wave (lanes l and l^32 are partners) ----
#pragma unroll
    for (int u = 0; u < 4; ++u)
#pragma unroll
        for (int v = 0; v < 4; ++v)
            acc[u][v] += __shfl_xor(acc[u][v], 32);

    // ---- epilogue: T into LDS (reuse Blds), then contract with W ----
    __syncthreads();
    if (bhalf == 0) {
#pragma unroll
        for (int u = 0; u < 4; ++u) {
            float4 q;
            q.x = acc[u][0]; q.y = acc[u][1]; q.z = acc[u][2]; q.w = acc[u][3];
            *(float4*)(&Blds[(a_loc * RM + (rmg * 4 + u)) * CIN + (jg << 2)]) = q;
        }
    }
    __syncthreads();

    if (t < ATILE * COUT) {
        const int al = t >> 4;
        const int i  = t & 15;
        float o0 = 0.f, o1 = 0.f;
        const float* T = &Blds[al * RM * CIN];
#pragma unroll
        for (int rm = 0; rm < RM; rm += 2) {
#pragma unroll
            for (int j = 0; j < CIN; j += 4) {
                float4 tv0 = *(const float4*)(T + rm * CIN + j);
                float4 wv0 = *(const float4*)(Wm + (rm * COUT + i) * CIN + j);
                o0 = fmaf(tv0.x, wv0.x, o0);
                o0 = fmaf(tv0.y, wv0.y, o0);
                o0 = fmaf(tv0.z, wv0.z, o0);
                o0 = fmaf(tv0.w, wv0.w, o0);
                float4 tv1 = *(const float4*)(T + (rm + 1) * CIN + j);
                float4 wv1 = *(const float4*)(Wm + ((rm + 1) * COUT + i) * CIN + j);
                o1 = fmaf(tv1.x, wv1.x, o1);
                o1 = fmaf(tv1.y, wv1.y, o1);
                o1 = fmaf(tv1.z, wv1.z, o1);
                o1 = fmaf(tv1.w, wv1.w, o1);
            }
        }
        const float scale = rsqrtf((float)n_norm[0]);  // 1/sqrt(512)
        out[(z * S + a0 + al) * COUT + i] = (o0 + o1) * scale;
    }
}

extern "C" void kernel_launch(void* const* d_in, const int* in_sizes, int n_in,
                              void* d_out, int out_size, void* d_ws, size_t ws_size,
                              hipStream_t stream) {
    const float* feat   = (const float*)d_in[0];
    const float* geomp  = (const float*)d_in[1];
    const float* Wm     = (const float*)d_in[2];
    const int*   n_norm = (const int*)d_in[3];
    float* outp = (float*)d_out;

    dim3 grid(512), block(256);
    econv_kernel<<<grid, block, 0, stream>>>(feat, geomp, Wm, n_norm, outp);
}

// Round 4
// 14.928 us; speedup vs baseline: 2.1314x; 2.0260x over previous
//
#include <hip/hip_runtime.h>
#include <hip/hip_fp16.h>

typedef _Float16 f16x8 __attribute__((ext_vector_type(8)));
typedef float    f32x4 __attribute__((ext_vector_type(4)));

#define S    512
#define CIN  16
#define COUT 16

static __device__ inline unsigned int pkrtz(float lo, float hi) {
    auto h = __builtin_amdgcn_cvt_pkrtz(lo, hi);   // __fp16 ext_vector(2)
    return __builtin_bit_cast(unsigned int, h);
}

// grid: 4 z * 128 a-groups = 512 blocks (2/CU, fully resident), 256 threads.
// One wave per a. T[rm,j] = sum_b Bas[b,rm] * F[b,j] via mfma_f32_16x16x32_f16:
//   A = Bas^T  (M=rm tile of 16, K=b)   from per-wave LDS [32 rm][128 b] fp16
//   B = F^T-fragments (K=b, N=j)        from per-block LDS [16 j][512 b] fp16
// Both operand fragments are contiguous-in-b 16B reads loaded with the SAME
// k-order, so the hardware's internal k permutation cancels.
__global__ __launch_bounds__(256, 2)
void econv_mfma(const float* __restrict__ feat,   // [4][512][16]
                const float* __restrict__ geom,   // [4][512][3]
                const float* __restrict__ Wm,     // [8][4][16][16] = [32 rm][16 i][16 j]
                const int*   __restrict__ n_norm, // [1]
                float*       __restrict__ out)    // [4][512][16]
{
    __shared__ float          Glds[S * 3];        // 6 KB
    __shared__ unsigned short FtU[16 * S];        // 16 KB  F^T fp16, swizzled
    __shared__ unsigned short BasU[4 * 32 * 128]; // 32 KB  per-wave Bas^T fp16, swizzled

    const int t = threadIdx.x;
    const int z = blockIdx.x >> 7;
    const int a0 = (blockIdx.x & 127) << 2;
    const int w = t >> 6;
    const int l = t & 63;

    const float* gz = geom + z * S * 3;
    const float* fz = feat + z * S * CIN;

    // ---- stage geometry (coalesced) ----
    for (int k = t; k < S * 3; k += 256) Glds[k] = gz[k];

    // ---- stage F^T fp16 swizzled: row j (1024 B), byte = j*1024 + (2b ^ ((j&7)<<4)) ----
    {
        const int j  = t & 15;
        const int b0 = (t >> 4) * 32;
        const int key = (j & 7) << 4;
        char* FtB = (char*)FtU;
#pragma unroll
        for (int bi = 0; bi < 32; bi += 2) {
            float f0 = fz[(b0 + bi) * CIN + j];
            float f1 = fz[(b0 + bi + 1) * CIN + j];
            *(unsigned int*)(FtB + j * 1024 + ((2 * (b0 + bi)) ^ key)) = pkrtz(f0, f1);
        }
    }
    __syncthreads();   // only barrier; waves are independent afterwards

    const int a = a0 + w;
    const float gax = Glds[3 * a], gay = Glds[3 * a + 1], gaz = Glds[3 * a + 2];

    char* BasB = (char*)(BasU + w * 32 * 128);
    char* FtB  = (char*)FtU;

    const int mrow = l & 15;           // rm row (tile0) == j row for B-frag == out i
    const int g    = l >> 4;
    const int rkey = (mrow & 7) << 4;  // read swizzle key (same for mrow and mrow+16)
    const int wbase = 4 * l;           // write byte base within a 256B Bas row

    f32x4 acc0 = {0.f, 0.f, 0.f, 0.f};
    f32x4 acc1 = {0.f, 0.f, 0.f, 0.f};

    for (int c = 0; c < 4; ++c) {
        // ---- basis for b = c*128 + 2l (h=0) and +1 (h=1), fp32 math ----
        float v0[32];
        unsigned int pw[32];
        {
            const int b = c * 128 + 2 * l;
            float dx = Glds[3 * b] - gax, dy = Glds[3 * b + 1] - gay, dz = Glds[3 * b + 2] - gaz;
            float ss  = fmaf(dx, dx, fmaf(dy, dy, fmaf(dz, dz, 1e-12f)));
            float inv = rsqrtf(ss);
            float d   = ss * inv;
            float ux = dx * inv, uy = dy * inv, uz = dz * inv;
#pragma unroll
            for (int r = 0; r < 8; ++r) {
                float e   = d - (float)r * (3.0f / 7.0f);
                float rad = __expf(-8.0f * e * e);
                v0[4 * r]     = rad;
                v0[4 * r + 1] = rad * ux;
                v0[4 * r + 2] = rad * uy;
                v0[4 * r + 3] = rad * uz;
            }
        }
        {
            const int b = c * 128 + 2 * l + 1;
            float dx = Glds[3 * b] - gax, dy = Glds[3 * b + 1] - gay, dz = Glds[3 * b + 2] - gaz;
            float ss  = fmaf(dx, dx, fmaf(dy, dy, fmaf(dz, dz, 1e-12f)));
            float inv = rsqrtf(ss);
            float d   = ss * inv;
            float ux = dx * inv, uy = dy * inv, uz = dz * inv;
#pragma unroll
            for (int r = 0; r < 8; ++r) {
                float e   = d - (float)r * (3.0f / 7.0f);
                float rad = __expf(-8.0f * e * e);
                pw[4 * r]     = pkrtz(v0[4 * r],     rad);
                pw[4 * r + 1] = pkrtz(v0[4 * r + 1], rad * ux);
                pw[4 * r + 2] = pkrtz(v0[4 * r + 2], rad * uy);
                pw[4 * r + 3] = pkrtz(v0[4 * r + 3], rad * uz);
            }
        }
        // scatter-write the two b-columns (packed u32) into Bas^T, swizzled: 2-way free
#pragma unroll
        for (int rm = 0; rm < 32; ++rm) {
            *(unsigned int*)(BasB + rm * 256 + (wbase ^ ((rm & 7) << 4))) = pw[rm];
        }

        // ---- 4 k-steps of MFMA over this 128-b chunk ----
#pragma unroll
        for (int ks = 0; ks < 4; ++ks) {
            const int colb = 64 * ks + 16 * g;   // byte offset of this lane-group's 8 b's
            f16x8 A0 = *(f16x8*)(BasB + mrow * 256        + (colb ^ rkey));
            f16x8 A1 = *(f16x8*)(BasB + (mrow + 16) * 256 + (colb ^ rkey));
            f16x8 Bf = *(f16x8*)(FtB  + mrow * 1024 + ((c * 256 + colb) ^ rkey));
            acc0 = __builtin_amdgcn_mfma_f32_16x16x32_f16(A0, Bf, acc0, 0, 0, 0);
            acc1 = __builtin_amdgcn_mfma_f32_16x16x32_f16(A1, Bf, acc1, 0, 0, 0);
        }
    }

    // ---- epilogue: T (fp32, reuse this wave's Bas slice) then contract with W ----
    float* Tl = (float*)BasB;   // [32 rm][16 j] fp32 = 2 KB
#pragma unroll
    for (int q = 0; q < 4; ++q) {
        Tl[(4 * g + q) * 16 + mrow]      = acc0[q];
        Tl[(16 + 4 * g + q) * 16 + mrow] = acc1[q];
    }

    float o = 0.f;
    const float* Wp = Wm + (g * 8) * COUT * CIN + mrow * CIN;  // W[g*8 + rr][i=mrow][j]
#pragma unroll
    for (int rr = 0; rr < 8; ++rr) {
        const float* Trow = Tl + (g * 8 + rr) * 16;
        const float* Wrow = Wp + rr * COUT * CIN;
#pragma unroll
        for (int j4 = 0; j4 < 4; ++j4) {
            f32x4 tv = *(const f32x4*)(Trow + 4 * j4);
            f32x4 wv = *(const f32x4*)(Wrow + 4 * j4);
            o = fmaf(tv[0], wv[0], o);
            o = fmaf(tv[1], wv[1], o);
            o = fmaf(tv[2], wv[2], o);
            o = fmaf(tv[3], wv[3], o);
        }
    }
    o += __shfl_xor(o, 16);
    o += __shfl_xor(o, 32);
    if (l < 16) {
        const float scale = rsqrtf((float)n_norm[0]);   // 1/sqrt(512)
        out[(z * S + a) * COUT + mrow] = o * scale;
    }
}

extern "C" void kernel_launch(void* const* d_in, const int* in_sizes, int n_in,
                              void* d_out, int out_size, void* d_ws, size_t ws_size,
                              hipStream_t stream) {
    const float* feat   = (const float*)d_in[0];
    const float* geomp  = (const float*)d_in[1];
    const float* Wm     = (const float*)d_in[2];
    const int*   n_norm = (const int*)d_in[3];
    float* outp = (float*)d_out;

    dim3 grid(512), block(256);
    econv_mfma<<<grid, block, 0, stream>>>(feat, geomp, Wm, n_norm, outp);
}